// Round 6
// baseline (2643.390 us; speedup 1.0000x reference)
//
#include <hip/hip_runtime.h>

// GRU decoder, B=256, H=512, T=512. 16 groups x 16 members = 256 WGs (1/CU).
// Member m holds 96 rows of W_hh in reg as bf16 MFMA A-frags. Per step:
// phase1 (waves 0-2): stream peers' h DIRECTLY from L2 into B-frags (relaxed
// agent u64 loads of split hi/lo planes, B-frag-ready layout col*32+k) and
// MFMA with 4 independent accumulator chains (tile x {hi,lo}).
// phase2 (waves 1-4): gates f32, export h hi/lo planes (sc1), stash hn in reg.
// sync (drains only exports) -> flag -> OUT store issues during poll window
// (wave 5 polls 16 member flags, relaxed agent, bounded spin + abort cascade).
// Round-5 fix: nontemporal store needs ext_vector type, not HIP float2.

typedef __attribute__((ext_vector_type(8))) short short8;
typedef __attribute__((ext_vector_type(4))) float f32x4;
typedef __attribute__((ext_vector_type(2))) float f32x2;
typedef unsigned short ushort_t;
typedef unsigned int uint_t;
typedef unsigned long long u64_t;

#define NG 16
#define NM 16
#define NB 16
#define NJ 32
#define TPB 384
#define SPIN_MAX (1u << 16)
#define ABORT_IDX 8192   // u32 index in flags region (byte 32768)
#define GBUF_BASE 16384  // u32 index of data region (byte 65536)
#define GRP_U32 8192     // per group per parity: 16 peers * (256 hi + 256 lo)
#define BUF_U32 131072   // per parity: 16 groups

#define ALD(P) __hip_atomic_load((P), __ATOMIC_RELAXED, __HIP_MEMORY_SCOPE_AGENT)

__device__ __forceinline__ ushort_t bf16_rne(float f) {
  uint_t u = __float_as_uint(f);
  return (ushort_t)((u + 0x7fffu + ((u >> 16) & 1u)) >> 16);
}
__device__ __forceinline__ float bf16f(ushort_t h) {
  return __uint_as_float(((uint_t)h) << 16);
}
__device__ __forceinline__ short8 mk8(u64_t a, u64_t b) {
  union {
    u64_t q[2];
    short8 s;
  } u;
  u.q[0] = a;
  u.q[1] = b;
  return u.s;
}
__device__ __forceinline__ int gRow(int rs, int m) {
  int base = m * NJ;
  if (rs < 32) return base + rs;
  if (rs < 64) return 512 + base + (rs - 32);
  return 1024 + base + (rs - 64);
}

template <bool LO>
__device__ __forceinline__ void loadW(short8* dst, const float* __restrict__ W,
                                      int tile, int m, int lane) {
  int rs = tile * 16 + (lane & 15);
  const float* p = W + (size_t)gRow(rs, m) * 512 + ((lane >> 4) << 3);
#pragma unroll
  for (int c = 0; c < 16; ++c) {
    const float* pc = p + c * 32;
    short8 o;
#pragma unroll
    for (int i = 0; i < 8; ++i) {
      float v = pc[i];
      ushort_t hi = bf16_rne(v);
      o[i] = LO ? (short)bf16_rne(v - bf16f(hi)) : (short)hi;
    }
    dst[c] = o;
  }
}

__global__ __launch_bounds__(TPB, 1) void gru_kernel(
    const float* __restrict__ x, const float* __restrict__ Wih,
    const float* __restrict__ Whh, const float* __restrict__ bih,
    const float* __restrict__ bhh, float* __restrict__ out,
    uint_t* __restrict__ wsp, int NT) {
  __shared__ __align__(16) char s_hhi[NB * 1024]; // relu(x) hi (gi phase only)
  __shared__ __align__(16) char s_hlo[NB * 1024]; // relu(x) lo
  __shared__ float s_gi[96 * 17];
  __shared__ float s_gh[96 * 17];
  __shared__ float s_hloc[NB * NJ]; // own h slice, f32 across steps
  __shared__ float s_bhh[NJ];
  __shared__ int s_stop;

  const int tid = threadIdx.x;
  const int lane = tid & 63;
  const int w = tid >> 6;
  const int bid = blockIdx.x;
  const int g = bid & 15; // same-XCD group
  const int m = bid >> 4;
  if (NT <= 0) return;

  uint_t* flags = wsp;
  uint_t* gbuf = wsp + GBUF_BASE;

  // ---- stage relu(x) as bf16 hi/lo into swizzled LDS (gi phase) ----
  for (int i = tid; i < NB * 64; i += TPB) {
    int b = i >> 6, k0 = (i & 63) << 3;
    const float* px = x + (size_t)(g * NB + b) * 512 + k0;
    short8 vh, vl;
#pragma unroll
    for (int ii = 0; ii < 8; ++ii) {
      float xv = px[ii];
      xv = xv > 0.f ? xv : 0.f;
      ushort_t hb = bf16_rne(xv);
      vh[ii] = (short)hb;
      vl[ii] = (short)bf16_rne(xv - bf16f(hb));
    }
    int off = ((b << 10) + (k0 << 1)) ^ ((b & 7) << 4);
    *(short8*)(s_hhi + off) = vh;
    *(short8*)(s_hlo + off) = vl;
  }
  if (tid < NJ) s_bhh[tid] = bhh[1024 + m * NJ + tid];
  if (tid == 0) s_stop = 0;
  __syncthreads();

  short8 wA[16], wB[16];
  const f32x4 vzero = {0.f, 0.f, 0.f, 0.f};
  f32x4 acc0 = vzero, acc1 = vzero;
  const int bcol = lane & 15;
  const int swzb = (bcol & 7) << 4;
  const int kb0 = (lane >> 4) << 4;

  // ---- gi = relu(x) @ W_ih^T (3-term hi/lo split) ----
  if (w < 3) {
    loadW<false>(wA, Wih, 2 * w, m, lane);
    loadW<false>(wB, Wih, 2 * w + 1, m, lane);
#pragma unroll
    for (int c = 0; c < 16; ++c) {
      int off = ((bcol << 10) + (c << 6) + kb0) ^ swzb;
      short8 bh = *(const short8*)(s_hhi + off);
      short8 bl = *(const short8*)(s_hlo + off);
      acc0 = __builtin_amdgcn_mfma_f32_16x16x32_bf16(wA[c], bh, acc0, 0, 0, 0);
      acc0 = __builtin_amdgcn_mfma_f32_16x16x32_bf16(wA[c], bl, acc0, 0, 0, 0);
      acc1 = __builtin_amdgcn_mfma_f32_16x16x32_bf16(wB[c], bh, acc1, 0, 0, 0);
      acc1 = __builtin_amdgcn_mfma_f32_16x16x32_bf16(wB[c], bl, acc1, 0, 0, 0);
    }
    loadW<true>(wA, Wih, 2 * w, m, lane);
    loadW<true>(wB, Wih, 2 * w + 1, m, lane);
#pragma unroll
    for (int c = 0; c < 16; ++c) {
      int off = ((bcol << 10) + (c << 6) + kb0) ^ swzb;
      short8 bh = *(const short8*)(s_hhi + off);
      acc0 = __builtin_amdgcn_mfma_f32_16x16x32_bf16(wA[c], bh, acc0, 0, 0, 0);
      acc1 = __builtin_amdgcn_mfma_f32_16x16x32_bf16(wB[c], bh, acc1, 0, 0, 0);
    }
  }
  __syncthreads();
  if (w < 3) {
    int drow = (lane >> 4) << 2;
#pragma unroll
    for (int q = 0; q < 4; ++q) {
      int rs0 = 2 * w * 16 + drow + q, rs1 = rs0 + 16;
      int g0 = gRow(rs0, m), g1 = gRow(rs1, m);
      s_gi[rs0 * 17 + bcol] = acc0[q] + bih[g0] + (rs0 < 64 ? bhh[g0] : 0.f);
      s_gi[rs1 * 17 + bcol] = acc1[q] + bih[g1] + (rs1 < 64 ? bhh[g1] : 0.f);
    }
    loadW<false>(wA, Whh, 2 * w, m, lane); // W_hh resident from here
    loadW<false>(wB, Whh, 2 * w + 1, m, lane);
  }
  for (int i = tid; i < NB * NJ; i += TPB) s_hloc[i] = 0.f;
  __syncthreads();

  const size_t outRow = (size_t)NT * 512;
  float* outBase = out + (size_t)(g * NB) * outRow + m * NJ;

  for (int t = 0; t < NT; ++t) {
    // ---- phase 1: gh = W_hh @ h, B-frags streamed straight from L2 ----
    if (w < 3) {
      // consume parity region (t&1): pre-zeroed for t=0 (h0=0)
      const u64_t* sq = (const u64_t*)gbuf + (size_t)(t & 1) * (BUF_U32 / 2) +
                        g * (GRP_U32 / 2);
      const int lofs = (bcol << 3) + ((lane >> 4) << 1);
      f32x4 a0h = vzero, a0l = vzero, a1h = vzero, a1l = vzero;
#pragma unroll
      for (int p = 0; p < 16; ++p) {
        const u64_t* pp = sq + p * 256 + lofs;
        u64_t h0 = ALD(pp);
        u64_t h1 = ALD(pp + 1);
        u64_t l0 = ALD(pp + 128);
        u64_t l1 = ALD(pp + 129);
        short8 bh = mk8(h0, h1), bl = mk8(l0, l1);
        a0h = __builtin_amdgcn_mfma_f32_16x16x32_bf16(wA[p], bh, a0h, 0, 0, 0);
        a1h = __builtin_amdgcn_mfma_f32_16x16x32_bf16(wB[p], bh, a1h, 0, 0, 0);
        a0l = __builtin_amdgcn_mfma_f32_16x16x32_bf16(wA[p], bl, a0l, 0, 0, 0);
        a1l = __builtin_amdgcn_mfma_f32_16x16x32_bf16(wB[p], bl, a1l, 0, 0, 0);
      }
      f32x4 r0 = a0h + a0l, r1 = a1h + a1l;
      int drow = (lane >> 4) << 2;
#pragma unroll
      for (int q = 0; q < 4; ++q) {
        s_gh[(2 * w * 16 + drow + q) * 17 + bcol] = r0[q];
        s_gh[((2 * w + 1) * 16 + drow + q) * 17 + bcol] = r1[q];
      }
    }
    __syncthreads();

    // ---- phase 2: gates on waves 1-4; export hi/lo planes (sc1) ----
    const int gt = tid - 64; // [0,256) for waves 1..4
    float hn0 = 0.f, hn1 = 0.f;
    uint_t* eb =
        gbuf + (size_t)((t & 1) ^ 1) * BUF_U32 + g * GRP_U32 + m * 512;
    if ((unsigned)gt < 256u) {
      int b = gt >> 4, j0 = (gt & 15) << 1;
      {
        int j = j0;
        float pr = s_gi[j * 17 + b] + s_gh[j * 17 + b];
        float pz = s_gi[(32 + j) * 17 + b] + s_gh[(32 + j) * 17 + b];
        float r = 1.f / (1.f + __expf(-pr));
        float z = 1.f / (1.f + __expf(-pz));
        float pn =
            s_gi[(64 + j) * 17 + b] + r * (s_gh[(64 + j) * 17 + b] + s_bhh[j]);
        float n = 1.f - 2.f / (1.f + __expf(2.f * pn));
        hn0 = n + z * (s_hloc[b * 32 + j] - n);
        s_hloc[b * 32 + j] = hn0;
      }
      {
        int j = j0 + 1;
        float pr = s_gi[j * 17 + b] + s_gh[j * 17 + b];
        float pz = s_gi[(32 + j) * 17 + b] + s_gh[(32 + j) * 17 + b];
        float r = 1.f / (1.f + __expf(-pr));
        float z = 1.f / (1.f + __expf(-pz));
        float pn =
            s_gi[(64 + j) * 17 + b] + r * (s_gh[(64 + j) * 17 + b] + s_bhh[j]);
        float n = 1.f - 2.f / (1.f + __expf(2.f * pn));
        hn1 = n + z * (s_hloc[b * 32 + j] - n);
        s_hloc[b * 32 + j] = hn1;
      }
      ushort_t hA = bf16_rne(hn0), hB = bf16_rne(hn1);
      uint_t phi = (uint_t)hA | ((uint_t)hB << 16);
      uint_t plo = (uint_t)bf16_rne(hn0 - bf16f(hA)) |
                   ((uint_t)bf16_rne(hn1 - bf16f(hB)) << 16);
      __hip_atomic_store(eb + gt, phi, __ATOMIC_RELAXED,
                         __HIP_MEMORY_SCOPE_AGENT);
      __hip_atomic_store(eb + 256 + gt, plo, __ATOMIC_RELAXED,
                         __HIP_MEMORY_SCOPE_AGENT);
    }
    __syncthreads(); // drains exports only (out not yet issued)

    if (tid == 256) // wave 4 lane 0: flag ASAP after the drain
      __hip_atomic_store(&flags[((g << 4) + m) << 5], (uint_t)(t + 1),
                         __ATOMIC_RELAXED, __HIP_MEMORY_SCOPE_AGENT);
    if ((unsigned)gt < 256u) { // out store overlaps the poll window
      int b = gt >> 4, j0 = (gt & 15) << 1;
      f32x2 ov = {hn0, hn1};
      __builtin_nontemporal_store(
          ov, (f32x2*)(outBase + (size_t)b * outRow + (size_t)t * 512 + j0));
    }
    if (w == 5 && t + 1 < NT) { // wave 5: clean-vmcnt poller
      const uint_t tgt = (uint_t)(t + 1);
      uint_t* fp = flags + (((g << 4) + (lane & 15)) << 5);
      uint_t sp = 0;
      for (;;) {
        uint_t v = 0xffffffffu;
        if (lane < 16) v = ALD(fp);
        if (__all((int)(v >= tgt))) break;
        ++sp;
        uint_t ab = 0;
        if ((sp & 127u) == 0u) {
          ab = ALD(&flags[ABORT_IDX]);
          if (sp > SPIN_MAX) {
            __hip_atomic_store(&flags[ABORT_IDX], 1u, __ATOMIC_RELAXED,
                               __HIP_MEMORY_SCOPE_AGENT);
            ab = 1;
          }
        }
        if (__any((int)(ab != 0))) {
          if (lane == 0) s_stop = 1;
          break;
        }
        __builtin_amdgcn_s_sleep(1);
      }
    }
    __syncthreads();
    if (s_stop) break;
  }
}

extern "C" void kernel_launch(void* const* d_in, const int* in_sizes, int n_in,
                              void* d_out, int out_size, void* d_ws,
                              size_t ws_size, hipStream_t stream) {
  const float* x = (const float*)d_in[0];
  const float* Wih = (const float*)d_in[1];
  const float* Whh = (const float*)d_in[2];
  const float* bih = (const float*)d_in[3];
  const float* bhh = (const float*)d_in[4];
  float* out = (float*)d_out;
  int NT = out_size / (256 * 512);
  // ws: [0,64KB) flags (128B-spaced) + abort; data @64KB: 2 x 512KB planes.
  // Zero flags + first parity region (h0 = 0 is read from it at t=0).
  uint_t* wsp = (uint_t*)d_ws;
  (void)hipMemsetAsync(d_ws, 0, 65536 + BUF_U32 * 4, stream);
  hipLaunchKernelGGL(gru_kernel, dim3(NG * NM), dim3(TPB), 0, stream, x, Wih,
                     Whh, bih, bhh, out, wsp, NT);
}

// Round 8
// 1293.831 us; speedup vs baseline: 2.0431x; 2.0431x over previous
//
#include <hip/hip_runtime.h>

// GRU decoder, B=256, H=512, T=512. 16 groups x 16 members = 256 WGs (1/CU).
// Round-7 structure (post-mortem r4/r6): batched reload -> LDS (one L3
// latency, zero unpack) + 4-chain MFMA + out-store off critical path.
// LDS plane layout per k-chunk/peer: [16 peers][hi 1KB | lo 1KB], bytes
// within plane = (b*64 + k*2) ^ ((b&7)<<4)  -> u64 reload writes and
// ds_read_b128 B-frag reads are both ~2-way (free). Exports: split planes
// (hi u32 [b][k/2], lo at +256) via relaxed agent atomics (sc1, no inv/wb).
// Sync: gates+export -> barrier(drain) -> flag -> out-store (overlaps poll)
// -> wave-5 poll (bounded spin + abort cascade) -> barrier -> reload -> barrier.
// [Round 8 = round 7 resubmitted verbatim: round 7 died on a dead container
// before the source was transmitted.]

typedef __attribute__((ext_vector_type(8))) short short8;
typedef __attribute__((ext_vector_type(4))) float f32x4;
typedef __attribute__((ext_vector_type(2))) float f32x2;
typedef __attribute__((ext_vector_type(4))) unsigned int u32x4;
typedef unsigned short ushort_t;
typedef unsigned int uint_t;
typedef unsigned long long u64_t;

#define NG 16
#define NM 16
#define NB 16
#define NJ 32
#define TPB 384
#define SPIN_MAX (1u << 16)
#define ABORT_IDX 8192   // u32 index in flags region (byte 32768)
#define GBUF_BASE 16384  // u32 index of data region (byte 65536)
#define GRP_U32 8192     // per group per parity: 16 members * 512 u32
#define BUF_U32 131072   // per parity: 16 groups

__device__ __forceinline__ uint_t ald32(const uint_t* p) {
  return __hip_atomic_load(p, __ATOMIC_RELAXED, __HIP_MEMORY_SCOPE_AGENT);
}
__device__ __forceinline__ u64_t ald64(const u64_t* p) {
  return __hip_atomic_load(p, __ATOMIC_RELAXED, __HIP_MEMORY_SCOPE_AGENT);
}
__device__ __forceinline__ ushort_t bf16_rne(float f) {
  uint_t u = __float_as_uint(f);
  return (ushort_t)((u + 0x7fffu + ((u >> 16) & 1u)) >> 16);
}
__device__ __forceinline__ float bf16f(ushort_t h) {
  return __uint_as_float(((uint_t)h) << 16);
}
__device__ __forceinline__ int gRow(int rs, int m) {
  int base = m * NJ;
  if (rs < 32) return base + rs;
  if (rs < 64) return 512 + base + (rs - 32);
  return 1024 + base + (rs - 64);
}

template <bool LO>
__device__ __forceinline__ void loadW(short8* dst, const float* __restrict__ W,
                                      int tile, int m, int lane) {
  int rs = tile * 16 + (lane & 15);
  const float* p = W + (size_t)gRow(rs, m) * 512 + ((lane >> 4) << 3);
#pragma unroll
  for (int c = 0; c < 16; ++c) {
    const float* pc = p + c * 32;
    short8 o;
#pragma unroll
    for (int i = 0; i < 8; ++i) {
      float v = pc[i];
      ushort_t hi = bf16_rne(v);
      o[i] = LO ? (short)bf16_rne(v - bf16f(hi)) : (short)hi;
    }
    dst[c] = o;
  }
}

__global__ __launch_bounds__(TPB, 1) void gru_kernel(
    const float* __restrict__ x, const float* __restrict__ Wih,
    const float* __restrict__ Whh, const float* __restrict__ bih,
    const float* __restrict__ bhh, float* __restrict__ out,
    uint_t* __restrict__ wsp, int NT) {
  __shared__ __align__(16) uint_t s_pb[16 * 512]; // 32KB swizzled planes
  __shared__ float s_gi[96 * 17];
  __shared__ float s_gh[96 * 17];
  __shared__ float s_hloc[NB * NJ]; // own h slice, f32 across steps
  __shared__ float s_bhh[NJ];
  __shared__ int s_stop;

  const int tid = threadIdx.x;
  const int lane = tid & 63;
  const int w = tid >> 6;
  const int bid = blockIdx.x;
  const int g = bid & 15; // same-XCD group
  const int m = bid >> 4;
  if (NT <= 0) return;

  uint_t* flags = wsp;
  uint_t* gbuf = wsp + GBUF_BASE;

  // ---- stage relu(x) as hi/lo planes (same layout as h planes) ----
  for (int i = tid; i < 1024; i += TPB) {
    int b = i >> 6, k0 = (i & 63) << 3;
    const float* px = x + (size_t)(g * NB + b) * 512 + k0;
    u32x4 vh, vl;
#pragma unroll
    for (int jj = 0; jj < 4; ++jj) {
      float f0 = px[2 * jj], f1 = px[2 * jj + 1];
      f0 = f0 > 0.f ? f0 : 0.f;
      f1 = f1 > 0.f ? f1 : 0.f;
      ushort_t h0 = bf16_rne(f0), h1 = bf16_rne(f1);
      vh[jj] = (uint_t)h0 | ((uint_t)h1 << 16);
      vl[jj] = (uint_t)bf16_rne(f0 - bf16f(h0)) |
               ((uint_t)bf16_rne(f1 - bf16f(h1)) << 16);
    }
    int c = k0 >> 5, kk = k0 & 31;
    int base = c * 2048 + (((b << 6) + (kk << 1)) ^ ((b & 7) << 4));
    *(u32x4*)((char*)s_pb + base) = vh;
    *(u32x4*)((char*)s_pb + base + 1024) = vl;
  }
  if (tid < NJ) s_bhh[tid] = bhh[1024 + m * NJ + tid];
  if (tid == 0) s_stop = 0;
  __syncthreads();

  short8 wA[16], wB[16];
  const f32x4 vzero = {0.f, 0.f, 0.f, 0.f};
  const int bcol = lane & 15;
  const int roff = ((bcol << 6) + ((lane >> 4) << 4)) ^ ((bcol & 7) << 4);
  const char* pb = (const char*)s_pb;

  // ---- gi = relu(x) @ W_ih^T (3-term hi/lo split) ----
  f32x4 acc0 = vzero, acc1 = vzero;
  if (w < 3) {
    loadW<false>(wA, Wih, 2 * w, m, lane);
    loadW<false>(wB, Wih, 2 * w + 1, m, lane);
    {
      f32x4 a0h = vzero, a0l = vzero, a1h = vzero, a1l = vzero;
#pragma unroll
      for (int c = 0; c < 16; ++c) {
        short8 bh = *(const short8*)(pb + c * 2048 + roff);
        short8 bl = *(const short8*)(pb + c * 2048 + 1024 + roff);
        a0h = __builtin_amdgcn_mfma_f32_16x16x32_bf16(wA[c], bh, a0h, 0, 0, 0);
        a1h = __builtin_amdgcn_mfma_f32_16x16x32_bf16(wB[c], bh, a1h, 0, 0, 0);
        a0l = __builtin_amdgcn_mfma_f32_16x16x32_bf16(wA[c], bl, a0l, 0, 0, 0);
        a1l = __builtin_amdgcn_mfma_f32_16x16x32_bf16(wB[c], bl, a1l, 0, 0, 0);
      }
      acc0 = a0h + a0l;
      acc1 = a1h + a1l;
    }
    loadW<true>(wA, Wih, 2 * w, m, lane);
    loadW<true>(wB, Wih, 2 * w + 1, m, lane);
#pragma unroll
    for (int c = 0; c < 16; ++c) {
      short8 bh = *(const short8*)(pb + c * 2048 + roff);
      acc0 = __builtin_amdgcn_mfma_f32_16x16x32_bf16(wA[c], bh, acc0, 0, 0, 0);
      acc1 = __builtin_amdgcn_mfma_f32_16x16x32_bf16(wB[c], bh, acc1, 0, 0, 0);
    }
  }
  __syncthreads();
  if (w < 3) {
    int drow = (lane >> 4) << 2;
#pragma unroll
    for (int q = 0; q < 4; ++q) {
      int rs0 = 2 * w * 16 + drow + q, rs1 = rs0 + 16;
      int g0 = gRow(rs0, m), g1 = gRow(rs1, m);
      s_gi[rs0 * 17 + bcol] = acc0[q] + bih[g0] + (rs0 < 64 ? bhh[g0] : 0.f);
      s_gi[rs1 * 17 + bcol] = acc1[q] + bih[g1] + (rs1 < 64 ? bhh[g1] : 0.f);
    }
    loadW<false>(wA, Whh, 2 * w, m, lane); // W_hh resident from here
    loadW<false>(wB, Whh, 2 * w + 1, m, lane);
  }
  for (int i = tid; i < 8192; i += TPB) s_pb[i] = 0u; // h0 = 0
  for (int i = tid; i < NB * NJ; i += TPB) s_hloc[i] = 0.f;
  __syncthreads();

  const size_t outRow = (size_t)NT * 512;
  float* outBase = out + (size_t)(g * NB) * outRow + m * NJ;

  for (int t = 0; t < NT; ++t) {
    // ---- phase 1: gh = W_hh @ h from LDS planes, 4 indep chains ----
    if (w < 3) {
      f32x4 a0h = vzero, a0l = vzero, a1h = vzero, a1l = vzero;
#pragma unroll
      for (int p = 0; p < 16; ++p) {
        short8 bh = *(const short8*)(pb + p * 2048 + roff);
        short8 bl = *(const short8*)(pb + p * 2048 + 1024 + roff);
        a0h = __builtin_amdgcn_mfma_f32_16x16x32_bf16(wA[p], bh, a0h, 0, 0, 0);
        a1h = __builtin_amdgcn_mfma_f32_16x16x32_bf16(wB[p], bh, a1h, 0, 0, 0);
        a0l = __builtin_amdgcn_mfma_f32_16x16x32_bf16(wA[p], bl, a0l, 0, 0, 0);
        a1l = __builtin_amdgcn_mfma_f32_16x16x32_bf16(wB[p], bl, a1l, 0, 0, 0);
      }
      f32x4 r0 = a0h + a0l, r1 = a1h + a1l;
      int drow = (lane >> 4) << 2;
#pragma unroll
      for (int q = 0; q < 4; ++q) {
        s_gh[(2 * w * 16 + drow + q) * 17 + bcol] = r0[q];
        s_gh[((2 * w + 1) * 16 + drow + q) * 17 + bcol] = r1[q];
      }
    }
    __syncthreads();

    // ---- phase 2: gates on waves 1-4; export hi/lo planes (sc1) ----
    const int gt = tid - 64; // [0,256) for waves 1..4
    float hn0 = 0.f, hn1 = 0.f;
    uint_t* eb =
        gbuf + (size_t)((t & 1) ^ 1) * BUF_U32 + g * GRP_U32 + m * 512;
    if ((unsigned)gt < 256u) {
      int b = gt >> 4, j0 = (gt & 15) << 1;
      {
        int j = j0;
        float pr = s_gi[j * 17 + b] + s_gh[j * 17 + b];
        float pz = s_gi[(32 + j) * 17 + b] + s_gh[(32 + j) * 17 + b];
        float r = 1.f / (1.f + __expf(-pr));
        float z = 1.f / (1.f + __expf(-pz));
        float pn =
            s_gi[(64 + j) * 17 + b] + r * (s_gh[(64 + j) * 17 + b] + s_bhh[j]);
        float n = 1.f - 2.f / (1.f + __expf(2.f * pn));
        hn0 = n + z * (s_hloc[b * 32 + j] - n);
        s_hloc[b * 32 + j] = hn0;
      }
      {
        int j = j0 + 1;
        float pr = s_gi[j * 17 + b] + s_gh[j * 17 + b];
        float pz = s_gi[(32 + j) * 17 + b] + s_gh[(32 + j) * 17 + b];
        float r = 1.f / (1.f + __expf(-pr));
        float z = 1.f / (1.f + __expf(-pz));
        float pn =
            s_gi[(64 + j) * 17 + b] + r * (s_gh[(64 + j) * 17 + b] + s_bhh[j]);
        float n = 1.f - 2.f / (1.f + __expf(2.f * pn));
        hn1 = n + z * (s_hloc[b * 32 + j] - n);
        s_hloc[b * 32 + j] = hn1;
      }
      ushort_t hA = bf16_rne(hn0), hB = bf16_rne(hn1);
      uint_t phi = (uint_t)hA | ((uint_t)hB << 16);
      uint_t plo = (uint_t)bf16_rne(hn0 - bf16f(hA)) |
                   ((uint_t)bf16_rne(hn1 - bf16f(hB)) << 16);
      __hip_atomic_store(eb + gt, phi, __ATOMIC_RELAXED,
                         __HIP_MEMORY_SCOPE_AGENT);
      __hip_atomic_store(eb + 256 + gt, plo, __ATOMIC_RELAXED,
                         __HIP_MEMORY_SCOPE_AGENT);
    }
    __syncthreads(); // drains exports only (out not yet issued)

    if (tid == 256) // flag ASAP after the drain
      __hip_atomic_store(&flags[((g << 4) + m) << 5], (uint_t)(t + 1),
                         __ATOMIC_RELAXED, __HIP_MEMORY_SCOPE_AGENT);
    if ((unsigned)gt < 256u) { // out store overlaps the poll window
      int b = gt >> 4, j0 = (gt & 15) << 1;
      f32x2 ov = {hn0, hn1};
      __builtin_nontemporal_store(
          ov, (f32x2*)(outBase + (size_t)b * outRow + (size_t)t * 512 + j0));
    }
    if (w == 5 && t + 1 < NT) { // wave 5: clean-vmcnt poller
      const uint_t tgt = (uint_t)(t + 1);
      uint_t* fp = flags + (((g << 4) + (lane & 15)) << 5);
      uint_t sp = 0;
      for (;;) {
        uint_t v = 0xffffffffu;
        if (lane < 16) v = ald32(fp);
        if (__all((int)(v >= tgt))) break;
        ++sp;
        uint_t ab = 0;
        if ((sp & 127u) == 0u) {
          ab = ald32(&flags[ABORT_IDX]);
          if (sp > SPIN_MAX) {
            __hip_atomic_store(&flags[ABORT_IDX], 1u, __ATOMIC_RELAXED,
                               __HIP_MEMORY_SCOPE_AGENT);
            ab = 1;
          }
        }
        if (__any((int)(ab != 0))) {
          if (lane == 0) s_stop = 1;
          break;
        }
        __builtin_amdgcn_s_sleep(1);
      }
    }
    __syncthreads();
    if (s_stop) break;

    // ---- reload: 11 batched u64 agent-loads -> swizzled LDS, no unpack ----
    if (t + 1 < NT) {
      const u64_t* srcq =
          (const u64_t*)(gbuf + (size_t)((t + 1) & 1) * BUF_U32 + g * GRP_U32);
#define LDI(k) ald64(srcq + tid + (k) * TPB)
      u64_t q0 = LDI(0), q1 = LDI(1), q2 = LDI(2), q3 = LDI(3), q4 = LDI(4);
      u64_t q5 = LDI(5), q6 = LDI(6), q7 = LDI(7), q8 = LDI(8), q9 = LDI(9);
      u64_t q10 = (tid < 256) ? LDI(10) : 0ull;
#undef LDI
#define STI(k, qq)                                                             \
  {                                                                            \
    uint_t qb = (uint_t)(tid + (k) * TPB) << 3;                                \
    *(u64_t*)((char*)s_pb + (qb ^ (((qb >> 6) & 7u) << 4))) = (qq);            \
  }
      STI(0, q0) STI(1, q1) STI(2, q2) STI(3, q3) STI(4, q4)
      STI(5, q5) STI(6, q6) STI(7, q7) STI(8, q8) STI(9, q9)
      if (tid < 256) STI(10, q10)
#undef STI
      __syncthreads();
    }
  }
}

extern "C" void kernel_launch(void* const* d_in, const int* in_sizes, int n_in,
                              void* d_out, int out_size, void* d_ws,
                              size_t ws_size, hipStream_t stream) {
  const float* x = (const float*)d_in[0];
  const float* Wih = (const float*)d_in[1];
  const float* Whh = (const float*)d_in[2];
  const float* bih = (const float*)d_in[3];
  const float* bhh = (const float*)d_in[4];
  float* out = (float*)d_out;
  int NT = out_size / (256 * 512);
  // ws: [0,64KB) flags (128B-spaced) + abort; data @64KB: 2 x 512KB planes.
  uint_t* wsp = (uint_t*)d_ws;
  (void)hipMemsetAsync(d_ws, 0, 65536, stream);
  hipLaunchKernelGGL(gru_kernel, dim3(NG * NM), dim3(TPB), 0, stream, x, Wih,
                     Whh, bih, bhh, out, wsp, NT);
}

// Round 11
// 1160.543 us; speedup vs baseline: 2.2777x; 1.1148x over previous
//
#include <hip/hip_runtime.h>

// GRU decoder, B=256, H=512, T=512. 16 groups x 16 members = 256 WGs (1/CU).
// Round-11: r8 skeleton (PROVEN relaxed-agent sc1 exchange; sc0 abandoned
// after r9/r10 steady-state deadlock) + two latency cuts:
//  (1) h exchanged as bf16 HI only (state stays f32; gi stays 3-term) ->
//      halves export/drain/reload/MFMA.
//  (2) poll+reload FUSION: waves 0-3 own 4 peers each -- poll those flags,
//      then immediately reload those peers' 512B into swizzled LDS (no
//      all-flags barrier before reload). Gates/export/out on waves 4-5.

typedef __attribute__((ext_vector_type(8))) short short8;
typedef __attribute__((ext_vector_type(4))) float f32x4;
typedef __attribute__((ext_vector_type(4))) unsigned int u32x4;
typedef unsigned short ushort_t;
typedef unsigned int uint_t;
typedef unsigned long long u64_t;

#define NG 16
#define NM 16
#define NB 16
#define NJ 32
#define TPB 384
#define SPIN_MAX (1u << 16)
#define ABORT_IDX 8192  // u32 idx: abort flag (flags region is 32KB)
#define GBUF_BASE 16384 // u32 idx of data region (byte 65536)
#define GRP_U32 4096    // per group per parity: 16 members * 256 u32 (hi only)
#define BUF_U32 65536   // per parity: 16 groups

#define ALD(P) __hip_atomic_load((P), __ATOMIC_RELAXED, __HIP_MEMORY_SCOPE_AGENT)
#define AST(P, V) __hip_atomic_store((P), (V), __ATOMIC_RELAXED, __HIP_MEMORY_SCOPE_AGENT)

__device__ __forceinline__ ushort_t bf16_rne(float f) {
  uint_t u = __float_as_uint(f);
  return (ushort_t)((u + 0x7fffu + ((u >> 16) & 1u)) >> 16);
}
__device__ __forceinline__ float bf16f(ushort_t h) {
  return __uint_as_float(((uint_t)h) << 16);
}
__device__ __forceinline__ int gRow(int rs, int m) {
  int base = m * NJ;
  if (rs < 32) return base + rs;
  if (rs < 64) return 512 + base + (rs - 32);
  return 1024 + base + (rs - 64);
}

template <bool LO>
__device__ __forceinline__ void loadW(short8* dst, const float* __restrict__ W,
                                      int tile, int m, int lane) {
  int rs = tile * 16 + (lane & 15);
  const float* p = W + (size_t)gRow(rs, m) * 512 + ((lane >> 4) << 3);
#pragma unroll
  for (int c = 0; c < 16; ++c) {
    const float* pc = p + c * 32;
    short8 o;
#pragma unroll
    for (int i = 0; i < 8; ++i) {
      float v = pc[i];
      ushort_t hi = bf16_rne(v);
      o[i] = LO ? (short)bf16_rne(v - bf16f(hi)) : (short)hi;
    }
    dst[c] = o;
  }
}

__global__ __launch_bounds__(TPB, 1) void gru_kernel(
    const float* __restrict__ x, const float* __restrict__ Wih,
    const float* __restrict__ Whh, const float* __restrict__ bih,
    const float* __restrict__ bhh, float* __restrict__ out,
    uint_t* __restrict__ wsp, int NT) {
  __shared__ __align__(16) uint_t s_pb[4096];  // 16KB: 16 chunks x 1KB (hi)
  __shared__ __align__(16) uint_t s_xlo[4096]; // 16KB: x lo-planes (gi only)
  __shared__ float s_gi[96 * 17];
  __shared__ float s_gh[96 * 17];
  __shared__ float s_hloc[NB * NJ]; // own h slice, f32 across steps
  __shared__ float s_bhh[NJ];
  __shared__ int s_stop;

  const int tid = threadIdx.x;
  const int lane = tid & 63;
  const int w = tid >> 6;
  const int bid = blockIdx.x;
  const int g = bid & 15; // same-XCD-leaning group mapping (perf only)
  const int m = bid >> 4;
  const int me = (g << 4) + m;
  if (NT <= 0) return;

  uint_t* flags = wsp;
  uint_t* gbuf = wsp + GBUF_BASE;

  // ---- stage relu(x) as hi plane (s_pb) + lo plane (s_xlo) ----
  for (int i = tid; i < 1024; i += TPB) {
    int b = i >> 6, k0 = (i & 63) << 3;
    const float* px = x + (size_t)(g * NB + b) * 512 + k0;
    u32x4 vh, vl;
#pragma unroll
    for (int jj = 0; jj < 4; ++jj) {
      float f0 = px[2 * jj], f1 = px[2 * jj + 1];
      f0 = f0 > 0.f ? f0 : 0.f;
      f1 = f1 > 0.f ? f1 : 0.f;
      ushort_t h0 = bf16_rne(f0), h1 = bf16_rne(f1);
      vh[jj] = (uint_t)h0 | ((uint_t)h1 << 16);
      vl[jj] = (uint_t)bf16_rne(f0 - bf16f(h0)) |
               ((uint_t)bf16_rne(f1 - bf16f(h1)) << 16);
    }
    int c = k0 >> 5, kk = k0 & 31;
    int base = c * 1024 + ((((b << 6) + (kk << 1))) ^ ((b & 7) << 4));
    *(u32x4*)((char*)s_pb + base) = vh;
    *(u32x4*)((char*)s_xlo + base) = vl;
  }
  if (tid < NJ) s_bhh[tid] = bhh[1024 + m * NJ + tid];
  if (tid == 0) s_stop = 0;
  __syncthreads();

  short8 wA[16], wB[16];
  const f32x4 vzero = {0.f, 0.f, 0.f, 0.f};
  const int bcol = lane & 15;
  const int roff = ((bcol << 6) + ((lane >> 4) << 4)) ^ ((bcol & 7) << 4);
  const char* pb = (const char*)s_pb;
  const char* pxl = (const char*)s_xlo;

  // ---- gi = relu(x) @ W_ih^T (3-term hi/lo split) ----
  f32x4 acc0 = vzero, acc1 = vzero;
  if (w < 3) {
    loadW<false>(wA, Wih, 2 * w, m, lane);
    loadW<false>(wB, Wih, 2 * w + 1, m, lane);
    {
      f32x4 a0h = vzero, a0l = vzero, a1h = vzero, a1l = vzero;
#pragma unroll
      for (int c = 0; c < 16; ++c) {
        short8 bh = *(const short8*)(pb + c * 1024 + roff);
        short8 bl = *(const short8*)(pxl + c * 1024 + roff);
        a0h = __builtin_amdgcn_mfma_f32_16x16x32_bf16(wA[c], bh, a0h, 0, 0, 0);
        a1h = __builtin_amdgcn_mfma_f32_16x16x32_bf16(wB[c], bh, a1h, 0, 0, 0);
        a0l = __builtin_amdgcn_mfma_f32_16x16x32_bf16(wA[c], bl, a0l, 0, 0, 0);
        a1l = __builtin_amdgcn_mfma_f32_16x16x32_bf16(wB[c], bl, a1l, 0, 0, 0);
      }
      acc0 = a0h + a0l;
      acc1 = a1h + a1l;
    }
    loadW<true>(wA, Wih, 2 * w, m, lane);
    loadW<true>(wB, Wih, 2 * w + 1, m, lane);
#pragma unroll
    for (int c = 0; c < 16; ++c) {
      short8 bh = *(const short8*)(pb + c * 1024 + roff);
      acc0 = __builtin_amdgcn_mfma_f32_16x16x32_bf16(wA[c], bh, acc0, 0, 0, 0);
      acc1 = __builtin_amdgcn_mfma_f32_16x16x32_bf16(wB[c], bh, acc1, 0, 0, 0);
    }
  }
  __syncthreads();
  if (w < 3) {
    int drow = (lane >> 4) << 2;
#pragma unroll
    for (int q = 0; q < 4; ++q) {
      int rs0 = 2 * w * 16 + drow + q, rs1 = rs0 + 16;
      int g0 = gRow(rs0, m), g1 = gRow(rs1, m);
      s_gi[rs0 * 17 + bcol] = acc0[q] + bih[g0] + (rs0 < 64 ? bhh[g0] : 0.f);
      s_gi[rs1 * 17 + bcol] = acc1[q] + bih[g1] + (rs1 < 64 ? bhh[g1] : 0.f);
    }
    loadW<false>(wA, Whh, 2 * w, m, lane); // W_hh resident from here
    loadW<false>(wB, Whh, 2 * w + 1, m, lane);
  }
  for (int i = tid; i < 4096; i += TPB) s_pb[i] = 0u; // h0 = 0
  for (int i = tid; i < NB * NJ; i += TPB) s_hloc[i] = 0.f;
  __syncthreads();

  const size_t outRow = (size_t)NT * 512;
  float* outBase = out + (size_t)(g * NB) * outRow + m * NJ;

  for (int t = 0; t < NT; ++t) {
    // ---- phase 1: gh = W_hh @ h_hi from LDS chunks (waves 0-2) ----
    if (w < 3) {
      f32x4 aE0 = vzero, aO0 = vzero, aE1 = vzero, aO1 = vzero;
#pragma unroll
      for (int p = 0; p < 16; p += 2) {
        short8 b0 = *(const short8*)(pb + p * 1024 + roff);
        short8 b1 = *(const short8*)(pb + (p + 1) * 1024 + roff);
        aE0 = __builtin_amdgcn_mfma_f32_16x16x32_bf16(wA[p], b0, aE0, 0, 0, 0);
        aE1 = __builtin_amdgcn_mfma_f32_16x16x32_bf16(wB[p], b0, aE1, 0, 0, 0);
        aO0 = __builtin_amdgcn_mfma_f32_16x16x32_bf16(wA[p + 1], b1, aO0, 0, 0, 0);
        aO1 = __builtin_amdgcn_mfma_f32_16x16x32_bf16(wB[p + 1], b1, aO1, 0, 0, 0);
      }
      f32x4 r0 = aE0 + aO0, r1 = aE1 + aO1;
      int drow = (lane >> 4) << 2;
#pragma unroll
      for (int q = 0; q < 4; ++q) {
        s_gh[(2 * w * 16 + drow + q) * 17 + bcol] = r0[q];
        s_gh[((2 * w + 1) * 16 + drow + q) * 17 + bcol] = r1[q];
      }
    }
    __syncthreads();

    // ---- phase 2: gates on waves 4-5 (4 elems/thread); export hi u64 ----
    const int et = tid - 256; // [0,128) for waves 4-5
    float hn[4];
    int eb_ = 0, ej0 = 0;
    if (et >= 0) {
      int b = et >> 3, j0 = (et & 7) << 2;
      eb_ = b;
      ej0 = j0;
#pragma unroll
      for (int e = 0; e < 4; ++e) {
        int j = j0 + e;
        float pr = s_gi[j * 17 + b] + s_gh[j * 17 + b];
        float pz = s_gi[(32 + j) * 17 + b] + s_gh[(32 + j) * 17 + b];
        float r = 1.f / (1.f + __expf(-pr));
        float z = 1.f / (1.f + __expf(-pz));
        float pn =
            s_gi[(64 + j) * 17 + b] + r * (s_gh[(64 + j) * 17 + b] + s_bhh[j]);
        float n = 1.f - 2.f / (1.f + __expf(2.f * pn));
        hn[e] = n + z * (s_hloc[b * 32 + j] - n);
        s_hloc[b * 32 + j] = hn[e];
      }
      uint_t w0 = (uint_t)bf16_rne(hn[0]) | ((uint_t)bf16_rne(hn[1]) << 16);
      uint_t w1 = (uint_t)bf16_rne(hn[2]) | ((uint_t)bf16_rne(hn[3]) << 16);
      u64_t pq = (u64_t)w0 | ((u64_t)w1 << 32);
      u64_t* eb64 =
          (u64_t*)(gbuf + (size_t)((t & 1) ^ 1) * BUF_U32 + g * GRP_U32);
      __hip_atomic_store(eb64 + (m << 7) + (eb_ << 3) + (et & 7), pq,
                         __ATOMIC_RELAXED, __HIP_MEMORY_SCOPE_AGENT);
    }
    __syncthreads(); // drains exports (out not yet issued)

    if (tid == 256) // flag ASAP after the drain
      AST(&flags[me << 5], (uint_t)(t + 1));
    if (et >= 0) { // out store overlaps the poll window
      f32x4 ov = {hn[0], hn[1], hn[2], hn[3]};
      __builtin_nontemporal_store(
          ov,
          (f32x4*)(outBase + (size_t)eb_ * outRow + (size_t)t * 512 + ej0));
    }
    // ---- fused poll+reload: wave w (<4) owns peers 4w..4w+3 ----
    if (w < 4 && t + 1 < NT) {
      const uint_t tgt = (uint_t)(t + 1);
      int ok = 1;
      {
        uint_t sp = 0;
        uint_t* fp = flags + (((g << 4) + (w << 2) + (lane & 3)) << 5);
        for (;;) {
          uint_t v = tgt;
          if (lane < 4) v = ALD(fp);
          if (__all((int)(v >= tgt))) break;
          ++sp;
          uint_t ab = 0;
          if ((sp & 127u) == 0u) {
            ab = ALD(&flags[ABORT_IDX]);
            if (sp > SPIN_MAX) {
              AST(&flags[ABORT_IDX], 1u);
              ab = 1;
            }
          }
          if (__any((int)(ab != 0))) {
            if (lane == 0) s_stop = 1;
            ok = 0;
            break;
          }
          __builtin_amdgcn_s_sleep(1);
        }
      }
      if (ok) { // reload this wave's 4 peers: 8 u64/lane, batched
        const u64_t* srcq =
            (const u64_t*)(gbuf + (size_t)((t + 1) & 1) * BUF_U32 +
                           g * GRP_U32) +
            (w << 9);
#define LDI(k)                                                                 \
  __hip_atomic_load(srcq + lane + ((k) << 6), __ATOMIC_RELAXED,                \
                    __HIP_MEMORY_SCOPE_AGENT)
        u64_t q0 = LDI(0), q1 = LDI(1), q2 = LDI(2), q3 = LDI(3);
        u64_t q4 = LDI(4), q5 = LDI(5), q6 = LDI(6), q7 = LDI(7);
#undef LDI
#define STI(k, qq)                                                             \
  {                                                                            \
    uint_t qb = (uint_t)(((w << 9) + lane + ((k) << 6)) << 3);                 \
    *(u64_t*)((char*)s_pb + (qb ^ (((qb >> 6) & 7u) << 4))) = (qq);            \
  }
        STI(0, q0) STI(1, q1) STI(2, q2) STI(3, q3)
        STI(4, q4) STI(5, q5) STI(6, q6) STI(7, q7)
#undef STI
      }
    }
    __syncthreads();
    if (s_stop) break;
  }
}

extern "C" void kernel_launch(void* const* d_in, const int* in_sizes, int n_in,
                              void* d_out, int out_size, void* d_ws,
                              size_t ws_size, hipStream_t stream) {
  const float* x = (const float*)d_in[0];
  const float* Wih = (const float*)d_in[1];
  const float* Whh = (const float*)d_in[2];
  const float* bih = (const float*)d_in[3];
  const float* bhh = (const float*)d_in[4];
  float* out = (float*)d_out;
  int NT = out_size / (256 * 512);
  // ws: [0,64KB) flags (128B-spaced) + abort; data @64KB: 2 x 256KB (hi only)
  uint_t* wsp = (uint_t*)d_ws;
  (void)hipMemsetAsync(d_ws, 0, 65536, stream);
  hipLaunchKernelGGL(gru_kernel, dim3(NG * NM), dim3(TPB), 0, stream, x, Wih,
                     Whh, bih, bhh, out, wsp, NT);
}